// Round 1
// baseline (470.540 us; speedup 1.0000x reference)
//
#include <hip/hip_runtime.h>
#include <cstdint>
#include <cstddef>

// ---- problem constants ----
#define B_   2
#define T_   2048
#define C_   2048
#define NH   16
#define NKV  4
#define HS   128
#define GQ   (NH / NKV)   // 4 query heads per kv head

typedef __attribute__((ext_vector_type(8))) __bf16 bf16x8;
typedef __attribute__((ext_vector_type(4))) float  f32x4;
typedef __attribute__((ext_vector_type(8))) unsigned short u16x8;

// round-to-nearest-even f32 -> bf16 (bit pattern)
__device__ __forceinline__ unsigned short f2bf(float f) {
  unsigned u = __builtin_bit_cast(unsigned, f);
  unsigned r = 0x7fffu + ((u >> 16) & 1u);
  return (unsigned short)((u + r) >> 16);
}

// async global->LDS, 16B per lane; LDS dest = wave-uniform base + lane*16
__device__ __forceinline__ void gload_lds16(const void* g, void* l) {
  __builtin_amdgcn_global_load_lds(
      (__attribute__((address_space(1))) void*)(g),
      (__attribute__((address_space(3))) void*)(l), 16, 0, 0);
}

// ---------------------------------------------------------------------------
// f32 -> bf16 cast, 4 elems/thread
// ---------------------------------------------------------------------------
__global__ void f32_to_bf16_k(const float* __restrict__ in,
                              unsigned short* __restrict__ out, int n4) {
  int i = blockIdx.x * 256 + threadIdx.x;
  if (i < n4) {
    float4 v = reinterpret_cast<const float4*>(in)[i];
    ushort4 o;
    o.x = f2bf(v.x); o.y = f2bf(v.y); o.z = f2bf(v.z); o.w = f2bf(v.w);
    reinterpret_cast<ushort4*>(out)[i] = o;
  }
}

// ---------------------------------------------------------------------------
// RoPE tables: cos/sin [T_][64]
// ---------------------------------------------------------------------------
__global__ void rope_tables_k(float* __restrict__ cosT, float* __restrict__ sinT) {
  int i = blockIdx.x * 256 + threadIdx.x;   // t*64 + f
  if (i >= T_ * 64) return;
  int t = i >> 6, f = i & 63;
  float inv = powf(10000.0f, -(float)f * (1.0f / 64.0f));
  float a = (float)t * inv;
  cosT[i] = cosf(a);
  sinT[i] = sinf(a);
}

// ---------------------------------------------------------------------------
// GEMM: C[m,n] = sum_k A[m,k]*B[n,k]   (A: MxK bf16, B: NxK bf16, C: MxN f32)
// 128x128 tile, BK=64, 4 waves (2x2), global_load_lds w/ pre-swizzled source.
// LDS layout: row-major [row][64], 8-elem (16B) chunks XOR-swizzled:
//   slot(row, ch) = ch ^ (row & 7)
// ---------------------------------------------------------------------------
__global__ __launch_bounds__(256)
void gemm_bt_k(const unsigned short* __restrict__ A,
               const unsigned short* __restrict__ B,
               float* __restrict__ C, int M, int N, int K) {
  __shared__ unsigned short As[128 * 64];
  __shared__ unsigned short Bs[128 * 64];
  const int tid = threadIdx.x;
  const int wid = tid >> 6, lane = tid & 63;
  const int lr = lane & 15, lg = lane >> 4;
  const int lx = lr & 7;
  const int bn = blockIdx.x, bm = blockIdx.y;
  const int wr = wid >> 1, wc = wid & 1;

  const unsigned short* Ag = A + (size_t)(bm * 128) * K;
  const unsigned short* Bg = B + (size_t)(bn * 128) * K;

  f32x4 acc[4][4] = {};

  for (int k0 = 0; k0 < K; k0 += 64) {
    __syncthreads();
    // stage A,B tiles: 1024 16B-chunks each; chunk ci -> row=ci>>3, slot=ci&7
    // global chunk = slot ^ (row&7)  (involution)
#pragma unroll
    for (int j = 0; j < 4; ++j) {
      int ci = (j * 4 + wid) * 64 + lane;
      int row = ci >> 3, s = ci & 7;
      int ch = s ^ (row & 7);
      gload_lds16(Ag + (size_t)row * K + k0 + ch * 8, &As[(j * 4 + wid) * 512]);
    }
#pragma unroll
    for (int j = 0; j < 4; ++j) {
      int ci = (j * 4 + wid) * 64 + lane;
      int row = ci >> 3, s = ci & 7;
      int ch = s ^ (row & 7);
      gload_lds16(Bg + (size_t)row * K + k0 + ch * 8, &Bs[(j * 4 + wid) * 512]);
    }
    __syncthreads();

#pragma unroll
    for (int kk = 0; kk < 2; ++kk) {
      bf16x8 af[4], bfr[4];
      const int ch = kk * 4 + lg;
      const int slot = ch ^ lx;            // row&7 == lr&7 for all frag rows
#pragma unroll
      for (int m = 0; m < 4; ++m) {
        int row = wr * 64 + m * 16 + lr;
        af[m] = *reinterpret_cast<const bf16x8*>(&As[row * 64 + slot * 8]);
      }
#pragma unroll
      for (int n = 0; n < 4; ++n) {
        int row = wc * 64 + n * 16 + lr;
        bfr[n] = *reinterpret_cast<const bf16x8*>(&Bs[row * 64 + slot * 8]);
      }
#pragma unroll
      for (int m = 0; m < 4; ++m)
#pragma unroll
        for (int n = 0; n < 4; ++n)
          acc[m][n] = __builtin_amdgcn_mfma_f32_16x16x32_bf16(af[m], bfr[n], acc[m][n], 0, 0, 0);
    }
  }

  // epilogue: C/D layout col=lane&15, row=(lane>>4)*4+j
#pragma unroll
  for (int m = 0; m < 4; ++m) {
    int grow = bm * 128 + wr * 64 + m * 16 + lg * 4;
#pragma unroll
    for (int n = 0; n < 4; ++n) {
      int gcol = bn * 128 + wc * 64 + n * 16 + lr;
#pragma unroll
      for (int j = 0; j < 4; ++j)
        C[(size_t)(grow + j) * N + gcol] = acc[m][n][j];
    }
  }
}

// ---------------------------------------------------------------------------
// RoPE + pack: qkv f32 [B*T,3072] -> Qb [B,H,T,D], Kb/Vb [B,Kv,T,D] (bf16)
// thread handles pair (d, d+64) of one head-slot; slots: 0..15 q, 16..19 k, 20..23 v
// ---------------------------------------------------------------------------
__global__ void rope_pack_k(const float* __restrict__ qkv,
                            const float* __restrict__ cosT,
                            const float* __restrict__ sinT,
                            unsigned short* __restrict__ Qb,
                            unsigned short* __restrict__ Kb,
                            unsigned short* __restrict__ Vb) {
  int i = blockIdx.x * 256 + threadIdx.x;
  if (i >= B_ * T_ * 24 * 64) return;
  int f = i & 63;
  int slot = (i >> 6) % 24;
  int bt = i / (64 * 24);
  int t = bt % T_, b = bt / T_;
  const float* row = qkv + (size_t)bt * 3072;
  float c = cosT[t * 64 + f], s = sinT[t * 64 + f];

  if (slot < 16) {
    int h = slot;
    float u0 = row[h * 128 + f], u1 = row[h * 128 + 64 + f];
    size_t o = ((size_t)(b * NH + h) * T_ + t) * HS;
    Qb[o + f]      = f2bf(u0 * c - u1 * s);
    Qb[o + 64 + f] = f2bf(u1 * c + u0 * s);
  } else if (slot < 20) {
    int h = slot - 16;
    float u0 = row[2048 + h * 128 + f], u1 = row[2048 + h * 128 + 64 + f];
    size_t o = ((size_t)(b * NKV + h) * T_ + t) * HS;
    Kb[o + f]      = f2bf(u0 * c - u1 * s);
    Kb[o + 64 + f] = f2bf(u1 * c + u0 * s);
  } else {
    int h = slot - 20;
    float u0 = row[2560 + h * 128 + f], u1 = row[2560 + h * 128 + 64 + f];
    size_t o = ((size_t)(b * NKV + h) * T_ + t) * HS;
    Vb[o + f]      = f2bf(u0);
    Vb[o + 64 + f] = f2bf(u1);
  }
}

// ---------------------------------------------------------------------------
// Causal flash attention, GQA.
// Block: 64 q-rows, 4 waves x 16 rows. KV tiles of 64.
// Q/K staged via swizzled global_load_lds ([64][128], 16-chunk rows,
//   slot = (ch&8) | ((ch&7)^(row&7)));
// V reg-staged TRANSPOSED into Vt[d][kv] with kv-chunk XOR swizzle;
// P round-trips through padded LDS (Ps[16][72]) to re-layout C/D -> A frag.
// Output Yb bf16 in [B,T,C] layout (feeds GEMM2 directly).
// ---------------------------------------------------------------------------
__global__ __launch_bounds__(256)
void attn_fwd_k(const unsigned short* __restrict__ Qb,
                const unsigned short* __restrict__ Kb,
                const unsigned short* __restrict__ Vb,
                unsigned short* __restrict__ Yb) {
  __shared__ unsigned short Qs[64 * 128];
  __shared__ unsigned short Ks[64 * 128];
  __shared__ unsigned short Vt[128 * 64];
  __shared__ unsigned short Ps[4][16 * 72];

  const int tid = threadIdx.x;
  const int wid = tid >> 6, lane = tid & 63;
  const int lr = lane & 15, lg = lane >> 4;
  const int lx = lr & 7;
  const int bh = blockIdx.y;
  const int b = bh >> 4, h = bh & 15;
  const int kvh = h >> 2;                       // h / GQ
  const int q0 = blockIdx.x << 6;

  const unsigned short* Qg = Qb + (size_t)bh * T_ * HS;
  const unsigned short* Kg = Kb + (size_t)(b * NKV + kvh) * T_ * HS;
  const unsigned short* Vg = Vb + (size_t)(b * NKV + kvh) * T_ * HS;

  // stage Q tile once (rows q0..q0+63)
#pragma unroll
  for (int j = 0; j < 4; ++j) {
    int ci = (j * 4 + wid) * 64 + lane;         // 1024 chunks
    int row = ci >> 4, s = ci & 15;
    int ch = (s & 8) | ((s & 7) ^ (row & 7));
    gload_lds16(Qg + (size_t)(q0 + row) * HS + ch * 8, &Qs[(j * 4 + wid) * 512]);
  }

  float m_r[4] = {-1e30f, -1e30f, -1e30f, -1e30f};
  float l_r[4] = {0.f, 0.f, 0.f, 0.f};
  f32x4 o_acc[8] = {};

  const int tmax = blockIdx.x;
  for (int t = 0; t <= tmax; ++t) {
    const int kv0 = t << 6;
    __syncthreads();
    // stage K tile
#pragma unroll
    for (int j = 0; j < 4; ++j) {
      int ci = (j * 4 + wid) * 64 + lane;
      int row = ci >> 4, s = ci & 15;
      int ch = (s & 8) | ((s & 7) ^ (row & 7));
      gload_lds16(Kg + (size_t)(kv0 + row) * HS + ch * 8, &Ks[(j * 4 + wid) * 512]);
    }
    // stage V transposed: Vt elem addr(d,kv) = d*64 + ((kv>>3)^(d&7))*8 + (kv&7)
#pragma unroll
    for (int j = 0; j < 4; ++j) {
      int d0 = (j * 4 + wid) * 8;
      u16x8 v = *reinterpret_cast<const u16x8*>(Vg + (size_t)(kv0 + lane) * HS + d0);
#pragma unroll
      for (int e = 0; e < 8; ++e) {
        int d = d0 + e;
        Vt[d * 64 + (((lane >> 3) ^ (d & 7)) << 3) + (lane & 7)] = v[e];
      }
    }
    __syncthreads();

    // S = Q K^T for this wave's 16 q-rows
    f32x4 sf[4] = {};
#pragma unroll
    for (int kk = 0; kk < 4; ++kk) {
      const int ch = kk * 4 + lg;
      const int slot = (ch & 8) | ((ch & 7) ^ lx);
      const int qrow = wid * 16 + lr;
      bf16x8 aq = *reinterpret_cast<const bf16x8*>(&Qs[qrow * HS + slot * 8]);
#pragma unroll
      for (int n = 0; n < 4; ++n) {
        int krow = n * 16 + lr;
        bf16x8 bk = *reinterpret_cast<const bf16x8*>(&Ks[krow * HS + slot * 8]);
        sf[n] = __builtin_amdgcn_mfma_f32_16x16x32_bf16(aq, bk, sf[n], 0, 0, 0);
      }
    }

    // online softmax (C/D: row = lg*4+r is q-row, col = n*16+lr is kv)
    const float scale = 0.08838834764831845f;   // 1/sqrt(128)
    float alpha_r[4];
#pragma unroll
    for (int r = 0; r < 4; ++r) {
      const int qg_ = q0 + wid * 16 + lg * 4 + r;
      float mx = -1e30f;
#pragma unroll
      for (int n = 0; n < 4; ++n) {
        float s = sf[n][r] * scale;
        int kvj = kv0 + n * 16 + lr;
        s = (kvj <= qg_) ? s : -1e30f;
        sf[n][r] = s;
        mx = fmaxf(mx, s);
      }
      mx = fmaxf(mx, __shfl_xor(mx, 1));
      mx = fmaxf(mx, __shfl_xor(mx, 2));
      mx = fmaxf(mx, __shfl_xor(mx, 4));
      mx = fmaxf(mx, __shfl_xor(mx, 8));
      float mnew = fmaxf(m_r[r], mx);
      float al = __expf(m_r[r] - mnew);
      float ps = 0.f;
#pragma unroll
      for (int n = 0; n < 4; ++n) {
        float p = __expf(sf[n][r] - mnew);
        sf[n][r] = p;
        ps += p;
      }
      ps += __shfl_xor(ps, 1);
      ps += __shfl_xor(ps, 2);
      ps += __shfl_xor(ps, 4);
      ps += __shfl_xor(ps, 8);
      l_r[r] = l_r[r] * al + ps;
      m_r[r] = mnew;
      alpha_r[r] = al;
    }
    // rescale O
#pragma unroll
    for (int df = 0; df < 8; ++df)
#pragma unroll
      for (int r = 0; r < 4; ++r)
        o_acc[df][r] *= alpha_r[r];

    // P -> LDS (bf16), padded rows of 72
#pragma unroll
    for (int n = 0; n < 4; ++n)
#pragma unroll
      for (int r = 0; r < 4; ++r)
        Ps[wid][(lg * 4 + r) * 72 + n * 16 + lr] = f2bf(sf[n][r]);

    // O += P V
#pragma unroll
    for (int kk = 0; kk < 2; ++kk) {
      bf16x8 ap = *reinterpret_cast<const bf16x8*>(&Ps[wid][lr * 72 + kk * 32 + lg * 8]);
      const int ch = kk * 4 + lg;
#pragma unroll
      for (int df = 0; df < 8; ++df) {
        int d = df * 16 + lr;
        bf16x8 bv = *reinterpret_cast<const bf16x8*>(&Vt[d * 64 + ((ch ^ lx) << 3)]);
        o_acc[df] = __builtin_amdgcn_mfma_f32_16x16x32_bf16(ap, bv, o_acc[df], 0, 0, 0);
      }
    }
  }

  // normalize + store Yb [B,T,C]
#pragma unroll
  for (int r = 0; r < 4; ++r) {
    const float inv = 1.0f / l_r[r];
    const int trow = q0 + wid * 16 + lg * 4 + r;
    size_t base = ((size_t)(b * T_ + trow)) * C_ + h * HS;
#pragma unroll
    for (int df = 0; df < 8; ++df)
      Yb[base + df * 16 + lr] = f2bf(o_acc[df][r] * inv);
  }
}

// ---------------------------------------------------------------------------
extern "C" void kernel_launch(void* const* d_in, const int* in_sizes, int n_in,
                              void* d_out, int out_size, void* d_ws, size_t ws_size,
                              hipStream_t stream) {
  const float* x     = (const float*)d_in[0];   // [2,2048,2048]
  const float* w_qkv = (const float*)d_in[1];   // [3072,2048]
  const float* w_out = (const float*)d_in[2];   // [2048,2048]
  float* out = (float*)d_out;                   // [2,2048,2048]

  char* ws = (char*)d_ws;
  size_t off = 0;
  auto carve = [&](size_t bytes) { char* p = ws + off; off += (bytes + 255) & ~(size_t)255; return p; };

  const size_t n_x = (size_t)B_ * T_ * C_;            // 8388608
  const size_t n_wqkv = (size_t)3072 * 2048;          // 6291456
  const size_t n_wout = (size_t)2048 * 2048;          // 4194304

  unsigned short* xb    = (unsigned short*)carve(n_x * 2);      // reused as Qb
  unsigned short* wqkvb = (unsigned short*)carve(n_wqkv * 2);
  unsigned short* woutb = (unsigned short*)carve(n_wout * 2);
  float*          qkv   = (float*)carve((size_t)B_ * T_ * 3072 * 4); // reused as Yb
  unsigned short* Kb    = (unsigned short*)carve((size_t)B_ * NKV * T_ * HS * 2);
  unsigned short* Vb    = (unsigned short*)carve((size_t)B_ * NKV * T_ * HS * 2);
  float*          cosT  = (float*)carve((size_t)T_ * 64 * 4);
  float*          sinT  = (float*)carve((size_t)T_ * 64 * 4);

  unsigned short* Qb = xb;                 // alias: xb dead after GEMM1
  unsigned short* Yb = (unsigned short*)qkv; // alias: qkv dead after rope_pack

  // 1) casts + tables
  f32_to_bf16_k<<<(int)(n_x / 4 / 256), 256, 0, stream>>>(x, xb, (int)(n_x / 4));
  f32_to_bf16_k<<<(int)(n_wqkv / 4 / 256), 256, 0, stream>>>(w_qkv, wqkvb, (int)(n_wqkv / 4));
  f32_to_bf16_k<<<(int)(n_wout / 4 / 256), 256, 0, stream>>>(w_out, woutb, (int)(n_wout / 4));
  rope_tables_k<<<(T_ * 64 + 255) / 256, 256, 0, stream>>>(cosT, sinT);

  // 2) qkv = x @ w_qkv^T   [4096 x 3072], K=2048
  gemm_bt_k<<<dim3(3072 / 128, 4096 / 128), 256, 0, stream>>>(xb, wqkvb, qkv, 4096, 3072, 2048);

  // 3) RoPE + pack to Qb/Kb/Vb (bf16)
  rope_pack_k<<<(B_ * T_ * 24 * 64) / 256, 256, 0, stream>>>(qkv, cosT, sinT, Qb, Kb, Vb);

  // 4) causal GQA flash attention -> Yb [B,T,C] bf16
  attn_fwd_k<<<dim3(T_ / 64, B_ * NH), 256, 0, stream>>>(Qb, Kb, Vb, Yb);

  // 5) out = Yb @ w_out^T   [4096 x 2048], K=2048
  gemm_bt_k<<<dim3(2048 / 128, 4096 / 128), 256, 0, stream>>>(Yb, woutb, out, 4096, 2048, 2048);
}